// Round 14
// baseline (223.872 us; speedup 1.0000x reference)
//
#include <hip/hip_runtime.h>
#include <hip/hip_bf16.h>
#include <math.h>

#define BB 32
#define NN 512

typedef _Float16 f16x8 __attribute__((ext_vector_type(8)));
typedef __fp16  fp16x2 __attribute__((ext_vector_type(2)));
typedef float f32x4 __attribute__((ext_vector_type(4)));

#define MFMA16(a, b, c) __builtin_amdgcn_mfma_f32_16x16x32_f16(a, b, c, 0, 0, 0)

union AF { f16x8 v; unsigned int u[4]; };

// ============ 16-row epilogue (k_front, 256 threads) ========================
// Per-(b,h) partial max over this block's 16 rows -> PRIVATE slot
// pmax[b][tile][h] (one writer per slot: no atomics, no init).
static __device__ __forceinline__ void epi16(
    const float* ctile, const float* asd_f, int row0, int t,
    float* __restrict__ s, float* __restrict__ dTg, _Float16* __restrict__ hpT,
    float* dmax_lds, float* __restrict__ pmax_out)
{
    int b = row0 >> 9, jb = row0 & 511;
    if (t < 128) {
        int rr = t >> 3, h = t & 7;
        float sv = 0.f, dv = 0.f;
#pragma unroll
        for (int f = 0; f < 64; ++f) {
            float hv = ctile[rr * 66 + f];
            sv = fmaf(hv, asd_f[f * 8 + h], sv);
            dv = fmaf(hv, asd_f[512 + f * 8 + h], dv);
        }
        s[((size_t)b * NN + jb + rr) * 8 + h] = sv;
        dTg[((size_t)b * 8 + h) * NN + jb + rr] = dv;
        dmax_lds[t] = dv;
    } else if (t < 256) {
        int t2 = t - 128;
        int f = t2 >> 1, jl = (t2 & 1) * 8;
        f16x8 hv;
#pragma unroll
        for (int e = 0; e < 8; ++e)
            hv[e] = (_Float16)ctile[(jl + e) * 66 + f];
        *(f16x8*)(hpT + ((size_t)b * 64 + f) * NN + jb + jl) = hv;
    }
    __syncthreads();
    if (t < 8) {
        float m = dmax_lds[t];
#pragma unroll
        for (int k = 1; k < 16; ++k) m = fmaxf(m, dmax_lds[t + 8 * k]);
        pmax_out[((size_t)b * 32 + (jb >> 4)) * 8 + t] = m;   // 32 tiles/batch
    }
}

// ============ 32-row epilogue (attn MODE 0, 512 threads) ====================
static __device__ __forceinline__ void epi32(
    const float* ctile, const float* asd_f, int row0, int t,
    float* __restrict__ s, float* __restrict__ dTg, _Float16* __restrict__ hpT,
    float* dmax_lds, float* __restrict__ pmax_out)
{
    int b = row0 >> 9, jb = row0 & 511;
    if (t < 256) {
        int rr = t >> 3, h = t & 7;
        float sv = 0.f, dv = 0.f;
#pragma unroll
        for (int f = 0; f < 64; ++f) {
            float hv = ctile[rr * 66 + f];
            sv = fmaf(hv, asd_f[f * 8 + h], sv);
            dv = fmaf(hv, asd_f[512 + f * 8 + h], dv);
        }
        s[((size_t)b * NN + jb + rr) * 8 + h] = sv;
        dTg[((size_t)b * 8 + h) * NN + jb + rr] = dv;
        dmax_lds[t] = dv;
    } else {
        int t2 = t - 256;
        int f = t2 >> 2, jl = (t2 & 3) * 8;
        f16x8 hv;
#pragma unroll
        for (int e = 0; e < 8; ++e)
            hv[e] = (_Float16)ctile[(jl + e) * 66 + f];
        *(f16x8*)(hpT + ((size_t)b * 64 + f) * NN + jb + jl) = hv;
    }
    __syncthreads();
    if (t < 8) {
        float m = dmax_lds[t];
#pragma unroll
        for (int k = 1; k < 32; ++k) m = fmaxf(m, dmax_lds[t + 8 * k]);
        pmax_out[((size_t)b * 16 + (jb >> 5)) * 8 + t] = m;   // 16 tiles/batch
    }
}

// ============ k_front: layer-0 GEMM + W1T prep ==============================
__global__ __launch_bounds__(256) void k_front(
    const float* __restrict__ x, const float* __restrict__ W0,
    const float* __restrict__ W1, _Float16* __restrict__ W1T,
    const float* __restrict__ a_src, const float* __restrict__ a_dst,
    float* __restrict__ s, float* __restrict__ dTg, _Float16* __restrict__ hpT,
    float* __restrict__ pmax)
{
    __shared__ float ctile[16 * 66];
    __shared__ float asd_f[1024];
    __shared__ float dmax[128];
    int t = threadIdx.x, row0 = blockIdx.x * 16;
    int lane = t & 63, w = t >> 6, cn = lane & 15, rq = lane >> 4;

    // ---- blocks 0..15: build W1T (4096 tasks, same mapping as old wt_prep)
    if (blockIdx.x < 16) {
        int task = blockIdx.x * 256 + t;       // 0..4095
        int n = task & 63, gabs = task >> 6;
        int c = gabs >> 3, g = gabs & 7;
        f16x8 hv;
#pragma unroll
        for (int e = 0; e < 8; ++e)
            hv[e] = (_Float16)W1[(size_t)(gabs * 8 + e) * 64 + n];
        *(f16x8*)(W1T + (size_t)n * 512 + c * 64 + (g ^ (n & 7)) * 8) = hv;
    }

    ((float4*)asd_f)[t] = (t < 128) ? ((const float4*)a_src)[t]
                                    : ((const float4*)a_dst)[t - 128];
    f32x4 acc;
#pragma unroll
    for (int e = 0; e < 4; ++e) acc[e] = 0.f;
    int nn0 = w * 16 + cn;
#pragma unroll
    for (int ks = 0; ks < 2; ++ks) {
        const float* xp = x + (size_t)(row0 + cn) * 64 + ks * 32 + rq * 8;
        float4 x0 = *(const float4*)xp, x1 = *(const float4*)(xp + 4);
        f16x8 ah = {(_Float16)x0.x, (_Float16)x0.y, (_Float16)x0.z, (_Float16)x0.w,
                    (_Float16)x1.x, (_Float16)x1.y, (_Float16)x1.z, (_Float16)x1.w};
        // bh[e] = W0^T[nn0][(ks*4+rq)*8+e] = W0[((ks*4+rq)*8+e)*64 + nn0]
        f16x8 bh;
#pragma unroll
        for (int e = 0; e < 8; ++e)
            bh[e] = (_Float16)W0[(size_t)((ks * 4 + rq) * 8 + e) * 64 + nn0];
        acc = MFMA16(ah, bh, acc);
    }
#pragma unroll
    for (int r = 0; r < 4; ++r)
        ctile[(rq * 4 + r) * 66 + w * 16 + cn] = acc[r];
    __syncthreads();
    epi16(ctile, asd_f, row0, t, s, dTg, hpT, dmax, pmax);
}

// ============ fused attention v14: BARRIER-FREE K-loop ======================
// Convoy hypothesis (r6/r7/r13 nulls): per-chunk __syncthreads locks all
// waves into the same phase -> VALU/MFMA/LDS times SUM instead of MAX (m114).
// Fix: delete the LDS double-buffer + all K-loop barriers; read hT fragments,
// adj, and dd DIRECTLY from L2/global (hpT = 64KB/batch, adj tile = 64KB,
// dd = 2KB/head -- all L2-resident; same zero-barrier pattern as gemm1's
// W1T loop). Waves drift -> pipes overlap across waves; setprio now sits in
// m191's phase-diverse +regime. Only wave-private Et tables remain in LDS.
#define PBUILD(AOUT, SV, C0, CB, AVv, REL, DDv, Ev, Ebv)                \
    do {                                                                \
        _Pragma("unroll")                                               \
        for (int e = 0; e < 8; e += 2) {                                \
            float pA[2];                                                \
            _Pragma("unroll")                                           \
            for (int q = 0; q < 2; ++q) {                               \
                int ee = e + q;                                         \
                bool con = (AVv[ee] != 0.f) || (ee == (REL));           \
                float e0 = SV + DDv[ee];                                \
                float p0 = (e0 >= 0.f) ? (C0) * Ev[ee] : (CB) * Ebv[ee];\
                pA[q] = (con && e0 != 0.f) ? p0 : 0.f;                  \
            }                                                           \
            fp16x2 ka = __builtin_amdgcn_cvt_pkrtz(pA[0], pA[1]);       \
            AOUT.u[e >> 1] = __builtin_bit_cast(unsigned int, ka);      \
        }                                                               \
    } while (0)

template<int MODE>
__global__ __launch_bounds__(512, 4) void k_attn_fused(
    const float* __restrict__ s, const float* __restrict__ dTg,
    const float* __restrict__ pmaxd, const _Float16* __restrict__ hpT,
    const float* __restrict__ adj,
    const _Float16* __restrict__ W1T,
    const float* __restrict__ a_src, const float* __restrict__ a_dst,
    float* __restrict__ s_out, float* __restrict__ dTg_out,
    _Float16* __restrict__ hpT_out, float* __restrict__ pmax_out,
    float* __restrict__ o_f)
{
    __shared__ __align__(16) char smem[40960];
    // K-loop touches ONLY Et @ 36864.. (8 waves x 128 f, wave-private);
    // epilogues reuse 0..36864 (disjoint from live Et during K-loop).

    int blk = blockIdx.x;                      // 0..511
    int vb = ((blk & 7) << 6) | (blk >> 3);    // XCD swizzle (512 = 8*64)
    int b = vb >> 4, i0 = (vb & 15) << 5;      // 32-row tile
    int row0 = vb * 32;                        // = b*512 + i0
    int t = threadIdx.x, lane = t & 63, w = t >> 6;   // w = head (0..7)
    int cn = lane & 15, rq = lane >> 4;
    int myrow = i0 + cn;                       // tile A row; tile B = +16

    const _Float16* hb = hpT + (size_t)b * 64 * NN;   // [64 f][512 j], plain
    const float* ddg  = dTg + ((size_t)b * 8 + w) * NN;
    const float* arAg = adj + ((size_t)b * NN + myrow) * NN;
    const float* arBg = arAg + (size_t)16 * NN;

    // md = max over partial-max slots for (b, head w); butterfly reduce
    constexpr int NT = (MODE == 0) ? 32 : 16;
    float md = pmaxd[((size_t)b * NT + (lane & (NT - 1))) * 8 + w];
#pragma unroll
    for (int off = NT >> 1; off; off >>= 1) md = fmaxf(md, __shfl_xor(md, off));

    float svA = s[((size_t)b * NN + myrow) * 8 + w];
    float svB = s[((size_t)b * NN + myrow + 16) * 8 + w];
    float MA = fmaxf(svA + md, 0.f);
    float MB = fmaxf(svB + md, 0.f);
    // per-row softmax factors (all <= 1): c0 = exp(sv+md-M), cb = exp(.2(sv+md)-M)
    float c0A = __expf(svA + md - MA), cbA = __expf(0.2f * (svA + md) - MA);
    float c0B = __expf(svB + md - MB), cbB = __expf(0.2f * (svB + md) - MB);
    int rq8 = rq * 8;

    f16x8 ones;
#pragma unroll
    for (int e = 0; e < 8; ++e) ones[e] = (_Float16)1.0f;

    f32x4 accA[4], accB[4], accrsA, accrsB;
#pragma unroll
    for (int e = 0; e < 4; ++e) { accrsA[e] = 0.f; accrsB[e] = 0.f; }
#pragma unroll
    for (int ft = 0; ft < 4; ++ft)
#pragma unroll
        for (int e = 0; e < 4; ++e) { accA[ft][e] = 0.f; accB[ft][e] = 0.f; }

    float* Et = (float*)(smem + 36864) + (w << 7);   // wave-private 512B

#pragma unroll 2
    for (int jcx = 0; jcx < 8; ++jcx) {
        int jc = jcx * 64;
        // ---- per-wave E/Eb tables for this chunk (2 exps/lane)
        {
            float ddj = ddg[jc + lane];
            Et[lane]      = __expf(ddj - md);
            Et[lane + 64] = __expf(0.2f * (ddj - md));
        }
        asm volatile("s_waitcnt lgkmcnt(0)" ::: "memory");  // same-wave RAW
#pragma unroll
        for (int ks = 0; ks < 2; ++ks) {
            int jo = ks * 32 + rq8;
            float dd[8], avA[8], avB[8], Ev[8], Ebv[8];
            *(float4*)&dd[0]  = *(const float4*)(ddg + jc + jo);
            *(float4*)&dd[4]  = *(const float4*)(ddg + jc + jo + 4);
            *(float4*)&Ev[0]  = *(const float4*)(Et + jo);
            *(float4*)&Ev[4]  = *(const float4*)(Et + jo + 4);
            *(float4*)&Ebv[0] = *(const float4*)(Et + 64 + jo);
            *(float4*)&Ebv[4] = *(const float4*)(Et + 64 + jo + 4);
            *(float4*)&avA[0] = *(const float4*)(arAg + jc + jo);
            *(float4*)&avA[4] = *(const float4*)(arAg + jc + jo + 4);
            *(float4*)&avB[0] = *(const float4*)(arBg + jc + jo);
            *(float4*)&avB[4] = *(const float4*)(arBg + jc + jo + 4);
            int relA = myrow - (jc + jo);
            int relB = relA + 16;
            AF aA, aB;
            PBUILD(aA, svA, c0A, cbA, avA, relA, dd, Ev, Ebv);
            PBUILD(aB, svB, c0B, cbB, avB, relB, dd, Ev, Ebv);
            __builtin_amdgcn_s_setprio(1);     // T5: phase-diverse regime now
            accrsA = MFMA16(aA.v, ones, accrsA);
            accrsB = MFMA16(aB.v, ones, accrsB);
#pragma unroll
            for (int ft = 0; ft < 4; ++ft) {   // 1 bh read -> 2 MFMAs
                // direct from L2-resident hpT (plain layout, no swizzle)
                f16x8 bh = *(const f16x8*)(hb + (size_t)(ft * 16 + cn) * NN + jc + jo);
                accA[ft] = MFMA16(aA.v, bh, accA[ft]);
                accB[ft] = MFMA16(aB.v, bh, accB[ft]);
            }
            __builtin_amdgcn_s_setprio(0);
        }
        // NO barrier — waves drift freely
    }

    float invrA[4], invrB[4];
#pragma unroll
    for (int r = 0; r < 4; ++r) {
        invrA[r] = 1.0f / accrsA[r];
        invrB[r] = 1.0f / accrsB[r];
    }

    if (MODE == 0) {
        _Float16* x1all = (_Float16*)smem;     // [8][32][64] fp16 = 32KB
#pragma unroll
        for (int rt = 0; rt < 2; ++rt)
#pragma unroll
            for (int ft = 0; ft < 4; ++ft)
#pragma unroll
                for (int r = 0; r < 4; ++r) {
                    int il = rt * 16 + rq * 4 + r;
                    float v = rt ? accB[ft][r] * invrB[r]
                                 : accA[ft][r] * invrA[r];
                    v = v > 0.f ? v : __expf(v) - 1.f;   // ELU
                    int f = ft * 16 + cn;
                    x1all[w * 2048 + il * 64 + (((f >> 3) ^ (il & 7)) * 8) + (f & 7)] =
                        (_Float16)v;
                }
        __syncthreads();
        f32x4 g1A, g1B;
#pragma unroll
        for (int e = 0; e < 4; ++e) { g1A[e] = 0.f; g1B[e] = 0.f; }
        int nn = (w & 3) * 16 + cn, kh = w >> 2;
        const _Float16* wb = W1T + (size_t)nn * 512;
#pragma unroll
        for (int kc2 = 0; kc2 < 4; ++kc2) {
            int kc = kh * 4 + kc2;
#pragma unroll
            for (int ks = 0; ks < 2; ++ks) {
                f16x8 bh = *(const f16x8*)(wb + kc * 64 +
                                           (((ks * 4 + rq) ^ (nn & 7)) * 8));
                f16x8 ahA = *(const f16x8*)&x1all[kc * 2048 + cn * 64 +
                                                  (((ks * 4 + rq) ^ (cn & 7)) * 8)];
                f16x8 ahB = *(const f16x8*)&x1all[kc * 2048 + (16 + cn) * 64 +
                                                  (((ks * 4 + rq) ^ (cn & 7)) * 8)];
                g1A = MFMA16(ahA, bh, g1A);
                g1B = MFMA16(ahB, bh, g1B);
            }
        }
        __syncthreads();                       // x1all reads done
        float* ct = (float*)smem;              // [2][32][66] = 16.9KB
        float* asd_f = (float*)(smem + 33280); // 4KB
        float* dmax = (float*)(smem + 37376);  // 1KB (Et dead)
#pragma unroll
        for (int r = 0; r < 4; ++r) {
            ct[kh * 2112 + (rq * 4 + r) * 66 + nn] = g1A[r];
            ct[kh * 2112 + (16 + rq * 4 + r) * 66 + nn] = g1B[r];
        }
        if (t < 256)
            ((float4*)asd_f)[t] = (t < 128) ? ((const float4*)a_src)[t]
                                            : ((const float4*)a_dst)[t - 128];
        __syncthreads();
        for (int idx = t; idx < 2112; idx += 512) ct[idx] += ct[2112 + idx];
        __syncthreads();
        epi32(ct, asd_f, row0, t, s_out, dTg_out, hpT_out, dmax, pmax_out);
    } else {
        float* red = (float*)smem;             // [4][32][64] fp32 = 32KB
#pragma unroll
        for (int ph = 0; ph < 2; ++ph) {
            if ((w >> 2) == ph) {
#pragma unroll
                for (int rt = 0; rt < 2; ++rt)
#pragma unroll
                    for (int ft = 0; ft < 4; ++ft)
#pragma unroll
                        for (int r = 0; r < 4; ++r) {
                            int il = rt * 16 + rq * 4 + r;
                            float v = rt ? accB[ft][r] * invrB[r]
                                         : accA[ft][r] * invrA[r];
                            int off = (w & 3) * 2048 + il * 64 + ft * 16 + cn;
                            if (ph == 0) red[off] = v;
                            else         red[off] += v;
                        }
            }
            __syncthreads();
        }
#pragma unroll
        for (int u = 0; u < 4; ++u) {
            int idx = t + u * 512;
            int il = idx >> 6, f = idx & 63;
            float sum = red[il * 64 + f] + red[2048 + il * 64 + f]
                      + red[4096 + il * 64 + f] + red[6144 + il * 64 + f];
            o_f[((size_t)b * NN + i0 + il) * 64 + f] = sum * 0.125f;
        }
    }
}

extern "C" void kernel_launch(void* const* d_in, const int* in_sizes, int n_in,
                              void* d_out, int out_size, void* d_ws, size_t ws_size,
                              hipStream_t stream) {
    const float* x      = (const float*)d_in[0];
    const float* adj    = (const float*)d_in[1];
    const float* W0     = (const float*)d_in[4];
    const float* a_src0 = (const float*)d_in[5];
    const float* a_dst0 = (const float*)d_in[6];
    const float* W1     = (const float*)d_in[7];
    const float* a_src1 = (const float*)d_in[8];
    const float* a_dst1 = (const float*)d_in[9];
    float* out = (float*)d_out;

    float* ws = (float*)d_ws;
    const size_t R = (size_t)BB * NN;            // 16384 rows
    const size_t BHN = (size_t)BB * 8 * NN;      // 131072
    float* s0    = ws;                           // R*8
    float* dTg0  = s0 + R * 8;
    float* s1    = dTg0 + BHN;
    float* dTg1  = s1 + R * 8;
    float* pmax0 = dTg1 + BHN;                   // 32*32*8 = 8192
    float* pmax1 = pmax0 + 8192;                 // 32*16*8 = 4096
    _Float16* hp0T = (_Float16*)(pmax1 + 4096);  // 32*64*512
    _Float16* hp1T = hp0T + (size_t)BB * 64 * NN;
    _Float16* W1T  = hp1T + (size_t)BB * 64 * NN;   // 64*512

    k_front<<<1024, 256, 0, stream>>>(x, W0, W1, W1T, a_src0, a_dst0,
                                      s0, dTg0, hp0T, pmax0);
    k_attn_fused<0><<<512, 512, 0, stream>>>(s0, dTg0, pmax0, hp0T, adj,
                                             W1T, a_src1, a_dst1,
                                             s1, dTg1, hp1T, pmax1, nullptr);
    k_attn_fused<1><<<512, 512, 0, stream>>>(s1, dTg1, pmax1, hp1T, adj,
                                             nullptr, nullptr, nullptr,
                                             nullptr, nullptr, nullptr, nullptr, out);
}

// Round 15
// 155.193 us; speedup vs baseline: 1.4425x; 1.4425x over previous
//
#include <hip/hip_runtime.h>
#include <hip/hip_bf16.h>
#include <math.h>

#define BB 32
#define NN 512

typedef _Float16 f16x8 __attribute__((ext_vector_type(8)));
typedef __fp16  fp16x2 __attribute__((ext_vector_type(2)));
typedef float f32x4 __attribute__((ext_vector_type(4)));

#define MFMA16(a, b, c) __builtin_amdgcn_mfma_f32_16x16x32_f16(a, b, c, 0, 0, 0)

union AF { f16x8 v; unsigned int u[4]; };

// async global->LDS; LDS dest = wave-uniform base + lane*size
__device__ __forceinline__ void gload_lds16(const void* g, void* l) {
    __builtin_amdgcn_global_load_lds(
        (const __attribute__((address_space(1))) unsigned int*)g,
        (__attribute__((address_space(3))) unsigned int*)l, 16, 0, 0);
}
__device__ __forceinline__ void gload_lds4(const void* g, void* l) {
    __builtin_amdgcn_global_load_lds(
        (const __attribute__((address_space(1))) unsigned int*)g,
        (__attribute__((address_space(3))) unsigned int*)l, 4, 0, 0);
}

// ============ 16-row epilogue (k_front, 256 threads) ========================
static __device__ __forceinline__ void epi16(
    const float* ctile, const float* asd_f, int row0, int t,
    float* __restrict__ s, float* __restrict__ dTg, _Float16* __restrict__ hpT,
    float* dmax_lds, float* __restrict__ pmax_out)
{
    int b = row0 >> 9, jb = row0 & 511;
    if (t < 128) {
        int rr = t >> 3, h = t & 7;
        float sv = 0.f, dv = 0.f;
#pragma unroll
        for (int f = 0; f < 64; ++f) {
            float hv = ctile[rr * 66 + f];
            sv = fmaf(hv, asd_f[f * 8 + h], sv);
            dv = fmaf(hv, asd_f[512 + f * 8 + h], dv);
        }
        s[((size_t)b * NN + jb + rr) * 8 + h] = sv;
        dTg[((size_t)b * 8 + h) * NN + jb + rr] = dv;
        dmax_lds[t] = dv;
    } else if (t < 256) {
        int t2 = t - 128;
        int f = t2 >> 1, jl = (t2 & 1) * 8;
        f16x8 hv;
#pragma unroll
        for (int e = 0; e < 8; ++e)
            hv[e] = (_Float16)ctile[(jl + e) * 66 + f];
        *(f16x8*)(hpT + ((size_t)b * 64 + f) * NN + jb + jl) = hv;
    }
    __syncthreads();
    if (t < 8) {
        float m = dmax_lds[t];
#pragma unroll
        for (int k = 1; k < 16; ++k) m = fmaxf(m, dmax_lds[t + 8 * k]);
        pmax_out[((size_t)b * 32 + (jb >> 4)) * 8 + t] = m;   // 32 tiles/batch
    }
}

// ============ 32-row epilogue (attn MODE 0, 512 threads) ====================
static __device__ __forceinline__ void epi32(
    const float* ctile, const float* asd_f, int row0, int t,
    float* __restrict__ s, float* __restrict__ dTg, _Float16* __restrict__ hpT,
    float* dmax_lds, float* __restrict__ pmax_out)
{
    int b = row0 >> 9, jb = row0 & 511;
    if (t < 256) {
        int rr = t >> 3, h = t & 7;
        float sv = 0.f, dv = 0.f;
#pragma unroll
        for (int f = 0; f < 64; ++f) {
            float hv = ctile[rr * 66 + f];
            sv = fmaf(hv, asd_f[f * 8 + h], sv);
            dv = fmaf(hv, asd_f[512 + f * 8 + h], dv);
        }
        s[((size_t)b * NN + jb + rr) * 8 + h] = sv;
        dTg[((size_t)b * 8 + h) * NN + jb + rr] = dv;
        dmax_lds[t] = dv;
    } else {
        int t2 = t - 256;
        int f = t2 >> 2, jl = (t2 & 3) * 8;
        f16x8 hv;
#pragma unroll
        for (int e = 0; e < 8; ++e)
            hv[e] = (_Float16)ctile[(jl + e) * 66 + f];
        *(f16x8*)(hpT + ((size_t)b * 64 + f) * NN + jb + jl) = hv;
    }
    __syncthreads();
    if (t < 8) {
        float m = dmax_lds[t];
#pragma unroll
        for (int k = 1; k < 32; ++k) m = fmaxf(m, dmax_lds[t + 8 * k]);
        pmax_out[((size_t)b * 16 + (jb >> 5)) * 8 + t] = m;   // 16 tiles/batch
    }
}

// ============ k_front: layer-0 GEMM + W1T prep ==============================
__global__ __launch_bounds__(256) void k_front(
    const float* __restrict__ x, const float* __restrict__ W0,
    const float* __restrict__ W1, _Float16* __restrict__ W1T,
    const float* __restrict__ a_src, const float* __restrict__ a_dst,
    float* __restrict__ s, float* __restrict__ dTg, _Float16* __restrict__ hpT,
    float* __restrict__ pmax)
{
    __shared__ float ctile[16 * 66];
    __shared__ float asd_f[1024];
    __shared__ float dmax[128];
    int t = threadIdx.x, row0 = blockIdx.x * 16;
    int lane = t & 63, w = t >> 6, cn = lane & 15, rq = lane >> 4;

    // ---- blocks 0..15: build W1T (4096 tasks, same mapping as old wt_prep)
    if (blockIdx.x < 16) {
        int task = blockIdx.x * 256 + t;       // 0..4095
        int n = task & 63, gabs = task >> 6;
        int c = gabs >> 3, g = gabs & 7;
        f16x8 hv;
#pragma unroll
        for (int e = 0; e < 8; ++e)
            hv[e] = (_Float16)W1[(size_t)(gabs * 8 + e) * 64 + n];
        *(f16x8*)(W1T + (size_t)n * 512 + c * 64 + (g ^ (n & 7)) * 8) = hv;
    }

    ((float4*)asd_f)[t] = (t < 128) ? ((const float4*)a_src)[t]
                                    : ((const float4*)a_dst)[t - 128];
    f32x4 acc;
#pragma unroll
    for (int e = 0; e < 4; ++e) acc[e] = 0.f;
    int nn0 = w * 16 + cn;
#pragma unroll
    for (int ks = 0; ks < 2; ++ks) {
        const float* xp = x + (size_t)(row0 + cn) * 64 + ks * 32 + rq * 8;
        float4 x0 = *(const float4*)xp, x1 = *(const float4*)(xp + 4);
        f16x8 ah = {(_Float16)x0.x, (_Float16)x0.y, (_Float16)x0.z, (_Float16)x0.w,
                    (_Float16)x1.x, (_Float16)x1.y, (_Float16)x1.z, (_Float16)x1.w};
        // bh[e] = W0^T[nn0][(ks*4+rq)*8+e] = W0[((ks*4+rq)*8+e)*64 + nn0]
        f16x8 bh;
#pragma unroll
        for (int e = 0; e < 8; ++e)
            bh[e] = (_Float16)W0[(size_t)((ks * 4 + rq) * 8 + e) * 64 + nn0];
        acc = MFMA16(ah, bh, acc);
    }
#pragma unroll
    for (int r = 0; r < 4; ++r)
        ctile[(rq * 4 + r) * 66 + w * 16 + cn] = acc[r];
    __syncthreads();
    epi16(ctile, asd_f, row0, t, s, dTg, hpT, dmax, pmax);
}

// ============ fused attention v15 ===========================================
// Revert to v12 pipeline (barrier'd global_load_lds double buffer — r14
// proved it's load-bearing latency hiding). MODE 0: identical hot loop +
// side-product adjb bitmask pack (~0.3us: masks it half-computes anyway).
// MODE 1: adj float path replaced by u64 bitmask loads (round-10p verbatim
// pattern) — removes 4 b128 LDS reads/ks + the adj staging stream.
#define PBUILD(AOUT, SV, C0, CB, CONE, DDv, Ev, Ebv)                    \
    do {                                                                \
        _Pragma("unroll")                                               \
        for (int e = 0; e < 8; e += 2) {                                \
            float pA[2];                                                \
            _Pragma("unroll")                                           \
            for (int q = 0; q < 2; ++q) {                               \
                int ee = e + q;                                         \
                bool con = (CONE);                                      \
                float e0 = SV + DDv[ee];                                \
                float p0 = (e0 >= 0.f) ? (C0) * Ev[ee] : (CB) * Ebv[ee];\
                pA[q] = (con && e0 != 0.f) ? p0 : 0.f;                  \
            }                                                           \
            fp16x2 ka = __builtin_amdgcn_cvt_pkrtz(pA[0], pA[1]);       \
            AOUT.u[e >> 1] = __builtin_bit_cast(unsigned int, ka);      \
        }                                                               \
    } while (0)

template<int MODE>
__global__ __launch_bounds__(512, 4) void k_attn_fused(
    const float* __restrict__ s, const float* __restrict__ dTg,
    const float* __restrict__ pmaxd, const _Float16* __restrict__ hpT,
    const float* __restrict__ adj,
    const unsigned long long* __restrict__ adjb_in,
    unsigned long long* __restrict__ adjb_out,
    const _Float16* __restrict__ W1T,
    const float* __restrict__ a_src, const float* __restrict__ a_dst,
    float* __restrict__ s_out, float* __restrict__ dTg_out,
    _Float16* __restrict__ hpT_out, float* __restrict__ pmax_out,
    float* __restrict__ o_f)
{
    __shared__ __align__(16) char smem[40960];
    constexpr int BUFB = (MODE == 0) ? 18432 : 10240;  // hT 8K|dd 2K[|adj 8K]
    char* bufP = smem;
    char* bufQ = smem + BUFB;
    // Et tables: 8 waves x 128 f @ 36864 (wave-private; disjoint from bufs)

    int blk = blockIdx.x;                      // 0..511
    int vb = ((blk & 7) << 6) | (blk >> 3);    // XCD swizzle (512 = 8*64)
    int b = vb >> 4, i0 = (vb & 15) << 5;      // 32-row tile
    int row0 = vb * 32;                        // = b*512 + i0
    int t = threadIdx.x, lane = t & 63, w = t >> 6;   // w = head (0..7)
    int cn = lane & 15, rq = lane >> 4;
    int myrow = i0 + cn;                       // tile A row; tile B = +16

    const _Float16* hb = hpT + (size_t)b * 64 * NN;
    int f0 = t >> 3, g0 = t & 7;
    const _Float16* hsrc = hb + (size_t)f0 * NN + ((g0 ^ (f0 & 7)) * 8);
    const float* dsrc = dTg + ((size_t)b * 8 + w) * NN + lane;
    // adj staging (MODE 0): thread covers row (t>>4), physical granule (t&15);
    // source pre-swizzled (involution; reader XORs the same way).
    int ar = t >> 4, ag = t & 15;
    const float* asrc = (MODE == 0)
        ? adj + (size_t)(row0 + ar) * NN + (((ag ^ (ar & 7))) << 2) : nullptr;

    auto stage = [&](char* BUF, int JC) {
        gload_lds16(hsrc + JC, (_Float16*)BUF + (w << 9));
        gload_lds4(dsrc + JC, (float*)(BUF + 8192) + (w << 6));
        if (MODE == 0)
            gload_lds16(asrc + JC, (float*)(BUF + 10240) + (w << 8));
    };

    stage(bufP, 0);                            // prologue: chunk 0 in flight

    // md = max over partial-max slots for (b, head w); butterfly reduce
    constexpr int NT = (MODE == 0) ? 32 : 16;
    float md = pmaxd[((size_t)b * NT + (lane & (NT - 1))) * 8 + w];
#pragma unroll
    for (int off = NT >> 1; off; off >>= 1) md = fmaxf(md, __shfl_xor(md, off));

    float svA = s[((size_t)b * NN + myrow) * 8 + w];
    float svB = s[((size_t)b * NN + myrow + 16) * 8 + w];
    float MA = fmaxf(svA + md, 0.f);
    float MB = fmaxf(svB + md, 0.f);
    // per-row softmax factors (all <= 1)
    float c0A = __expf(svA + md - MA), cbA = __expf(0.2f * (svA + md) - MA);
    float c0B = __expf(svB + md - MB), cbB = __expf(0.2f * (svB + md) - MB);
    int rq8 = rq * 8;

    // MODE 1: bitmask row pointers + 1-chunk lookahead (round-10p pattern)
    const unsigned long long* abr = (MODE == 1)
        ? adjb_in + ((size_t)b * NN + myrow) * 8 : nullptr;
    unsigned long long mbA = 0, mbB = 0;
    if (MODE == 1) { mbA = abr[0]; mbB = abr[128]; }
    // MODE 0: adjb output rows
    unsigned long long* aoA = (MODE == 0)
        ? adjb_out + ((size_t)b * NN + myrow) * 8 : nullptr;

    f16x8 ones;
#pragma unroll
    for (int e = 0; e < 8; ++e) ones[e] = (_Float16)1.0f;

    f32x4 accA[4], accB[4], accrsA, accrsB;
#pragma unroll
    for (int e = 0; e < 4; ++e) { accrsA[e] = 0.f; accrsB[e] = 0.f; }
#pragma unroll
    for (int ft = 0; ft < 4; ++ft)
#pragma unroll
        for (int e = 0; e < 4; ++e) { accA[ft][e] = 0.f; accB[ft][e] = 0.f; }

    float* Et = (float*)(smem + 36864) + (w << 7);   // wave-private 512B

    __syncthreads();                           // buf0 staged

    for (int jcx = 0; jcx < 8; ++jcx) {
        int jc = jcx * 64;
        char* cur = (jcx & 1) ? bufQ : bufP;
        char* nxt = (jcx & 1) ? bufP : bufQ;
        if (jcx < 7) stage(nxt, jc + 64);      // lands during this chunk
        unsigned long long mbnA = 0, mbnB = 0;
        if (MODE == 1 && jcx < 7) { mbnA = abr[jcx + 1]; mbnB = abr[jcx + 129]; }
        const _Float16* hTc = (const _Float16*)cur;
        const float* ddl = (const float*)(cur + 8192) + (w << 6);
        const float* adl = (const float*)(cur + 10240);
        const float* arA = adl + cn * 64;
        const float* arB = adl + (16 + cn) * 64;
        int xA = cn & 7;
        unsigned int mlA = (unsigned)mbA, mhA = (unsigned)(mbA >> 32);
        unsigned int mlB = (unsigned)mbB, mhB = (unsigned)(mbB >> 32);
        // ---- per-wave E/Eb tables for this chunk (2 exps/lane)
        {
            float ddj = ddl[lane];
            Et[lane]      = __expf(ddj - md);
            Et[lane + 64] = __expf(0.2f * (ddj - md));
        }
        asm volatile("s_waitcnt lgkmcnt(0)" ::: "memory");  // same-wave RAW
        unsigned long long u64A = 0, u64B = 0;             // MODE0 pack acc
#pragma unroll
        for (int ks = 0; ks < 2; ++ks) {
            int jo = ks * 32 + rq8;
            float dd[8], Ev[8], Ebv[8];
            *(float4*)&dd[0]  = *(const float4*)(ddl + jo);
            *(float4*)&dd[4]  = *(const float4*)(ddl + jo + 4);
            *(float4*)&Ev[0]  = *(const float4*)(Et + jo);
            *(float4*)&Ev[4]  = *(const float4*)(Et + jo + 4);
            *(float4*)&Ebv[0] = *(const float4*)(Et + 64 + jo);
            *(float4*)&Ebv[4] = *(const float4*)(Et + 64 + jo + 4);
            int relA = myrow - (jc + jo);
            int relB = relA + 16;
            AF aA, aB;
            if (MODE == 0) {
                float avA[8], avB[8];
                int G0 = jo >> 2;              // granule index of jo
                *(float4*)&avA[0] = *(const float4*)(arA + ((G0 ^ xA) << 2));
                *(float4*)&avA[4] = *(const float4*)(arA + (((G0 + 1) ^ xA) << 2));
                *(float4*)&avB[0] = *(const float4*)(arB + ((G0 ^ xA) << 2));
                *(float4*)&avB[4] = *(const float4*)(arB + (((G0 + 1) ^ xA) << 2));
                // side product: 8-bit connectivity masks -> u64 pack
                unsigned mskA = 0, mskB = 0;
#pragma unroll
                for (int e = 0; e < 8; ++e) {
                    if (avA[e] != 0.f || e == relA) mskA |= 1u << e;
                    if (avB[e] != 0.f || e == relB) mskB |= 1u << e;
                }
                u64A |= (unsigned long long)mskA << (ks * 32 + rq8);
                u64B |= (unsigned long long)mskB << (ks * 32 + rq8);
                PBUILD(aA, svA, c0A, cbA, (avA[ee] != 0.f || ee == relA), dd, Ev, Ebv);
                PBUILD(aB, svB, c0B, cbB, (avB[ee] != 0.f || ee == relB), dd, Ev, Ebv);
            } else {
                unsigned int mbyA = ((ks ? mhA : mlA) >> rq8) & 0xffu;
                unsigned int mbyB = ((ks ? mhB : mlB) >> rq8) & 0xffu;
                PBUILD(aA, svA, c0A, cbA, ((mbyA >> ee) & 1u), dd, Ev, Ebv);
                PBUILD(aB, svB, c0B, cbB, ((mbyB >> ee) & 1u), dd, Ev, Ebv);
            }
            accrsA = MFMA16(aA.v, ones, accrsA);
            accrsB = MFMA16(aB.v, ones, accrsB);
#pragma unroll
            for (int ft = 0; ft < 4; ++ft) {   // 1 bh read -> 2 MFMAs
                int f = ft * 16 + cn;
                f16x8 bh = *(const f16x8*)&hTc[f * 64 + (((ks * 4 + rq) ^ (f & 7)) * 8)];
                accA[ft] = MFMA16(aA.v, bh, accA[ft]);
                accB[ft] = MFMA16(aB.v, bh, accB[ft]);
            }
        }
        if (MODE == 0) {                       // OR across the 4 rq lanes
            u64A |= __shfl_xor(u64A, 16); u64A |= __shfl_xor(u64A, 32);
            u64B |= __shfl_xor(u64B, 16); u64B |= __shfl_xor(u64B, 32);
            if (rq == 0) { aoA[jcx] = u64A; aoA[128 + jcx] = u64B; }
        }
        if (MODE == 1) { mbA = mbnA; mbB = mbnB; }
        __syncthreads();                       // drains next-chunk staging too
    }

    float invrA[4], invrB[4];
#pragma unroll
    for (int r = 0; r < 4; ++r) {
        invrA[r] = 1.0f / accrsA[r];
        invrB[r] = 1.0f / accrsB[r];
    }

    if (MODE == 0) {
        _Float16* x1all = (_Float16*)smem;     // [8][32][64] fp16 = 32KB
#pragma unroll
        for (int rt = 0; rt < 2; ++rt)
#pragma unroll
            for (int ft = 0; ft < 4; ++ft)
#pragma unroll
                for (int r = 0; r < 4; ++r) {
                    int il = rt * 16 + rq * 4 + r;
                    float v = rt ? accB[ft][r] * invrB[r]
                                 : accA[ft][r] * invrA[r];
                    v = v > 0.f ? v : __expf(v) - 1.f;   // ELU
                    int f = ft * 16 + cn;
                    x1all[w * 2048 + il * 64 + (((f >> 3) ^ (il & 7)) * 8) + (f & 7)] =
                        (_Float16)v;
                }
        __syncthreads();
        f32x4 g1A, g1B;
#pragma unroll
        for (int e = 0; e < 4; ++e) { g1A[e] = 0.f; g1B[e] = 0.f; }
        int nn = (w & 3) * 16 + cn, kh = w >> 2;
        const _Float16* wb = W1T + (size_t)nn * 512;
#pragma unroll
        for (int kc2 = 0; kc2 < 4; ++kc2) {
            int kc = kh * 4 + kc2;
#pragma unroll
            for (int ks = 0; ks < 2; ++ks) {
                f16x8 bh = *(const f16x8*)(wb + kc * 64 +
                                           (((ks * 4 + rq) ^ (nn & 7)) * 8));
                f16x8 ahA = *(const f16x8*)&x1all[kc * 2048 + cn * 64 +
                                                  (((ks * 4 + rq) ^ (cn & 7)) * 8)];
                f16x8 ahB = *(const f16x8*)&x1all[kc * 2048 + (16 + cn) * 64 +
                                                  (((ks * 4 + rq) ^ (cn & 7)) * 8)];
                g1A = MFMA16(ahA, bh, g1A);
                g1B = MFMA16(ahB, bh, g1B);
            }
        }
        __syncthreads();                       // x1all reads done
        float* ct = (float*)smem;              // [2][32][66] = 16.9KB
        float* asd_f = (float*)(smem + 33280); // 4KB
        float* dmax = (float*)(smem + 37376);  // 1KB (Et dead)
#pragma unroll
        for (int r = 0; r < 4; ++r) {
            ct[kh * 2112 + (rq * 4 + r) * 66 + nn] = g1A[r];
            ct[kh * 2112 + (16 + rq * 4 + r) * 66 + nn] = g1B[r];
        }
        if (t < 256)
            ((float4*)asd_f)[t] = (t < 128) ? ((const float4*)a_src)[t]
                                            : ((const float4*)a_dst)[t - 128];
        __syncthreads();
        for (int idx = t; idx < 2112; idx += 512) ct[idx] += ct[2112 + idx];
        __syncthreads();
        epi32(ct, asd_f, row0, t, s_out, dTg_out, hpT_out, dmax, pmax_out);
    } else {
        float* red = (float*)smem;             // [4][32][64] fp32 = 32KB
#pragma unroll
        for (int ph = 0; ph < 2; ++ph) {
            if ((w >> 2) == ph) {
#pragma unroll
                for (int rt = 0; rt < 2; ++rt)
#pragma unroll
                    for (int ft = 0; ft < 4; ++ft)
#pragma unroll
                        for (int r = 0; r < 4; ++r) {
                            int il = rt * 16 + rq * 4 + r;
                            float v = rt ? accB[ft][r] * invrB[r]
                                         : accA[ft][r] * invrA[r];
                            int off = (w & 3) * 2048 + il * 64 + ft * 16 + cn;
                            if (ph == 0) red[off] = v;
                            else         red[off] += v;
                        }
            }
            __syncthreads();
        }
#pragma unroll
        for (int u = 0; u < 4; ++u) {
            int idx = t + u * 512;
            int il = idx >> 6, f = idx & 63;
            float sum = red[il * 64 + f] + red[2048 + il * 64 + f]
                      + red[4096 + il * 64 + f] + red[6144 + il * 64 + f];
            o_f[((size_t)b * NN + i0 + il) * 64 + f] = sum * 0.125f;
        }
    }
}

extern "C" void kernel_launch(void* const* d_in, const int* in_sizes, int n_in,
                              void* d_out, int out_size, void* d_ws, size_t ws_size,
                              hipStream_t stream) {
    const float* x      = (const float*)d_in[0];
    const float* adj    = (const float*)d_in[1];
    const float* W0     = (const float*)d_in[4];
    const float* a_src0 = (const float*)d_in[5];
    const float* a_dst0 = (const float*)d_in[6];
    const float* W1     = (const float*)d_in[7];
    const float* a_src1 = (const float*)d_in[8];
    const float* a_dst1 = (const float*)d_in[9];
    float* out = (float*)d_out;

    float* ws = (float*)d_ws;
    const size_t R = (size_t)BB * NN;            // 16384 rows
    const size_t BHN = (size_t)BB * 8 * NN;      // 131072
    float* s0    = ws;                           // R*8
    float* dTg0  = s0 + R * 8;
    float* s1    = dTg0 + BHN;
    float* dTg1  = s1 + R * 8;
    float* pmax0 = dTg1 + BHN;                   // 32*32*8 = 8192
    float* pmax1 = pmax0 + 8192;                 // 32*16*8 = 4096
    _Float16* hp0T = (_Float16*)(pmax1 + 4096);  // 32*64*512
    _Float16* hp1T = hp0T + (size_t)BB * 64 * NN;
    _Float16* W1T  = hp1T + (size_t)BB * 64 * NN;   // 64*512
    unsigned long long* adjb = (unsigned long long*)(W1T + (size_t)64 * 512); // 16384*8 u64... (R*8 u64 = 1MB)

    k_front<<<1024, 256, 0, stream>>>(x, W0, W1, W1T, a_src0, a_dst0,
                                      s0, dTg0, hp0T, pmax0);
    k_attn_fused<0><<<512, 512, 0, stream>>>(s0, dTg0, pmax0, hp0T, adj,
                                             nullptr, adjb,
                                             W1T, a_src1, a_dst1,
                                             s1, dTg1, hp1T, pmax1, nullptr);
    k_attn_fused<1><<<512, 512, 0, stream>>>(s1, dTg1, pmax1, hp1T, nullptr,
                                             adjb, nullptr,
                                             nullptr, nullptr, nullptr,
                                             nullptr, nullptr, nullptr, nullptr, out);
}

// Round 16
// 152.364 us; speedup vs baseline: 1.4693x; 1.0186x over previous
//
#include <hip/hip_runtime.h>
#include <hip/hip_bf16.h>
#include <math.h>

#define BB 32
#define NN 512

typedef _Float16 f16x8 __attribute__((ext_vector_type(8)));
typedef __fp16  fp16x2 __attribute__((ext_vector_type(2)));
typedef float f32x4 __attribute__((ext_vector_type(4)));

#define MFMA16(a, b, c) __builtin_amdgcn_mfma_f32_16x16x32_f16(a, b, c, 0, 0, 0)

union AF { f16x8 v; unsigned int u[4]; };

// async global->LDS; LDS dest = wave-uniform base + lane*size
__device__ __forceinline__ void gload_lds16(const void* g, void* l) {
    __builtin_amdgcn_global_load_lds(
        (const __attribute__((address_space(1))) unsigned int*)g,
        (__attribute__((address_space(3))) unsigned int*)l, 16, 0, 0);
}
__device__ __forceinline__ void gload_lds4(const void* g, void* l) {
    __builtin_amdgcn_global_load_lds(
        (const __attribute__((address_space(1))) unsigned int*)g,
        (__attribute__((address_space(3))) unsigned int*)l, 4, 0, 0);
}

// ============ 16-row epilogue (k_front, 256 threads) ========================
// Per-(b,h) partial max over this block's 16 rows -> PRIVATE slot
// pmax[b][tile][h] (one writer per slot: no atomics, no init).
static __device__ __forceinline__ void epi16(
    const float* ctile, const float* asd_f, int row0, int t,
    float* __restrict__ s, float* __restrict__ dTg, _Float16* __restrict__ hpT,
    float* dmax_lds, float* __restrict__ pmax_out)
{
    int b = row0 >> 9, jb = row0 & 511;
    if (t < 128) {
        int rr = t >> 3, h = t & 7;
        float sv = 0.f, dv = 0.f;
#pragma unroll
        for (int f = 0; f < 64; ++f) {
            float hv = ctile[rr * 66 + f];
            sv = fmaf(hv, asd_f[f * 8 + h], sv);
            dv = fmaf(hv, asd_f[512 + f * 8 + h], dv);
        }
        s[((size_t)b * NN + jb + rr) * 8 + h] = sv;
        dTg[((size_t)b * 8 + h) * NN + jb + rr] = dv;
        dmax_lds[t] = dv;
    } else if (t < 256) {
        int t2 = t - 128;
        int f = t2 >> 1, jl = (t2 & 1) * 8;
        f16x8 hv;
#pragma unroll
        for (int e = 0; e < 8; ++e)
            hv[e] = (_Float16)ctile[(jl + e) * 66 + f];
        *(f16x8*)(hpT + ((size_t)b * 64 + f) * NN + jb + jl) = hv;
    }
    __syncthreads();
    if (t < 8) {
        float m = dmax_lds[t];
#pragma unroll
        for (int k = 1; k < 16; ++k) m = fmaxf(m, dmax_lds[t + 8 * k]);
        pmax_out[((size_t)b * 32 + (jb >> 4)) * 8 + t] = m;   // 32 tiles/batch
    }
}

// ============ 32-row epilogue (attn MODE 0, 512 threads) ====================
static __device__ __forceinline__ void epi32(
    const float* ctile, const float* asd_f, int row0, int t,
    float* __restrict__ s, float* __restrict__ dTg, _Float16* __restrict__ hpT,
    float* dmax_lds, float* __restrict__ pmax_out)
{
    int b = row0 >> 9, jb = row0 & 511;
    if (t < 256) {
        int rr = t >> 3, h = t & 7;
        float sv = 0.f, dv = 0.f;
#pragma unroll
        for (int f = 0; f < 64; ++f) {
            float hv = ctile[rr * 66 + f];
            sv = fmaf(hv, asd_f[f * 8 + h], sv);
            dv = fmaf(hv, asd_f[512 + f * 8 + h], dv);
        }
        s[((size_t)b * NN + jb + rr) * 8 + h] = sv;
        dTg[((size_t)b * 8 + h) * NN + jb + rr] = dv;
        dmax_lds[t] = dv;
    } else {
        int t2 = t - 256;
        int f = t2 >> 2, jl = (t2 & 3) * 8;
        f16x8 hv;
#pragma unroll
        for (int e = 0; e < 8; ++e)
            hv[e] = (_Float16)ctile[(jl + e) * 66 + f];
        *(f16x8*)(hpT + ((size_t)b * 64 + f) * NN + jb + jl) = hv;
    }
    __syncthreads();
    if (t < 8) {
        float m = dmax_lds[t];
#pragma unroll
        for (int k = 1; k < 32; ++k) m = fmaxf(m, dmax_lds[t + 8 * k]);
        pmax_out[((size_t)b * 16 + (jb >> 5)) * 8 + t] = m;   // 16 tiles/batch
    }
}

// ============ k_front: layer-0 GEMM + W1T prep ==============================
__global__ __launch_bounds__(256) void k_front(
    const float* __restrict__ x, const float* __restrict__ W0,
    const float* __restrict__ W1, _Float16* __restrict__ W1T,
    const float* __restrict__ a_src, const float* __restrict__ a_dst,
    float* __restrict__ s, float* __restrict__ dTg, _Float16* __restrict__ hpT,
    float* __restrict__ pmax)
{
    __shared__ float ctile[16 * 66];
    __shared__ float asd_f[1024];
    __shared__ float dmax[128];
    int t = threadIdx.x, row0 = blockIdx.x * 16;
    int lane = t & 63, w = t >> 6, cn = lane & 15, rq = lane >> 4;

    // ---- blocks 0..15: build W1T (4096 tasks, same mapping as old wt_prep)
    if (blockIdx.x < 16) {
        int task = blockIdx.x * 256 + t;       // 0..4095
        int n = task & 63, gabs = task >> 6;
        int c = gabs >> 3, g = gabs & 7;
        f16x8 hv;
#pragma unroll
        for (int e = 0; e < 8; ++e)
            hv[e] = (_Float16)W1[(size_t)(gabs * 8 + e) * 64 + n];
        *(f16x8*)(W1T + (size_t)n * 512 + c * 64 + (g ^ (n & 7)) * 8) = hv;
    }

    ((float4*)asd_f)[t] = (t < 128) ? ((const float4*)a_src)[t]
                                    : ((const float4*)a_dst)[t - 128];
    f32x4 acc;
#pragma unroll
    for (int e = 0; e < 4; ++e) acc[e] = 0.f;
    int nn0 = w * 16 + cn;
#pragma unroll
    for (int ks = 0; ks < 2; ++ks) {
        const float* xp = x + (size_t)(row0 + cn) * 64 + ks * 32 + rq * 8;
        float4 x0 = *(const float4*)xp, x1 = *(const float4*)(xp + 4);
        f16x8 ah = {(_Float16)x0.x, (_Float16)x0.y, (_Float16)x0.z, (_Float16)x0.w,
                    (_Float16)x1.x, (_Float16)x1.y, (_Float16)x1.z, (_Float16)x1.w};
        // bh[e] = W0^T[nn0][(ks*4+rq)*8+e] = W0[((ks*4+rq)*8+e)*64 + nn0]
        f16x8 bh;
#pragma unroll
        for (int e = 0; e < 8; ++e)
            bh[e] = (_Float16)W0[(size_t)((ks * 4 + rq) * 8 + e) * 64 + nn0];
        acc = MFMA16(ah, bh, acc);
    }
#pragma unroll
    for (int r = 0; r < 4; ++r)
        ctile[(rq * 4 + r) * 66 + w * 16 + cn] = acc[r];
    __syncthreads();
    epi16(ctile, asd_f, row0, t, s, dTg, hpT, dmax, pmax);
}

// ============ fused attention v12: factored softmax, LDS tables =============
// Best-measured configuration (153.0 us, round 12). Barrier'd global_load_lds
// double-buffer (r14 proved it's load-bearing); per-chunk wave-private E/Eb
// tables make the P-build exp-free:
//   p = (e0>=0) ? c0*E[j] : cb*Eb[j]   (all factors <= 1; ==0 quirk via e0)
#define PBUILD(AOUT, SV, C0, CB, AVv, REL, DDv, Ev, Ebv)                \
    do {                                                                \
        _Pragma("unroll")                                               \
        for (int e = 0; e < 8; e += 2) {                                \
            float pA[2];                                                \
            _Pragma("unroll")                                           \
            for (int q = 0; q < 2; ++q) {                               \
                int ee = e + q;                                         \
                bool con = (AVv[ee] != 0.f) || (ee == (REL));           \
                float e0 = SV + DDv[ee];                                \
                float p0 = (e0 >= 0.f) ? (C0) * Ev[ee] : (CB) * Ebv[ee];\
                pA[q] = (con && e0 != 0.f) ? p0 : 0.f;                  \
            }                                                           \
            fp16x2 ka = __builtin_amdgcn_cvt_pkrtz(pA[0], pA[1]);       \
            AOUT.u[e >> 1] = __builtin_bit_cast(unsigned int, ka);      \
        }                                                               \
    } while (0)

template<int MODE>
__global__ __launch_bounds__(512, 4) void k_attn_fused(
    const float* __restrict__ s, const float* __restrict__ dTg,
    const float* __restrict__ pmaxd, const _Float16* __restrict__ hpT,
    const float* __restrict__ adj,
    const _Float16* __restrict__ W1T,
    const float* __restrict__ a_src, const float* __restrict__ a_dst,
    float* __restrict__ s_out, float* __restrict__ dTg_out,
    _Float16* __restrict__ hpT_out, float* __restrict__ pmax_out,
    float* __restrict__ o_f)
{
    __shared__ __align__(16) char smem[40960];
    char* bufP = smem;                         // hT 8K | dd 2K | adj 8K
    char* bufQ = smem + 18432;
    // E/Eb tables: 8 waves x 128 floats @ smem+36864 (wave-private)

    int blk = blockIdx.x;                      // 0..511
    int vb = ((blk & 7) << 6) | (blk >> 3);    // XCD swizzle (512 = 8*64)
    int b = vb >> 4, i0 = (vb & 15) << 5;      // 32-row tile
    int row0 = vb * 32;                        // = b*512 + i0
    int t = threadIdx.x, lane = t & 63, w = t >> 6;   // w = head (0..7)
    int cn = lane & 15, rq = lane >> 4;
    int myrow = i0 + cn;                       // tile A row; tile B = +16

    const _Float16* hb = hpT + (size_t)b * 64 * NN;
    int f0 = t >> 3, g0 = t & 7;
    const _Float16* hsrc = hb + (size_t)f0 * NN + ((g0 ^ (f0 & 7)) * 8);
    const float* dsrc = dTg + ((size_t)b * 8 + w) * NN + lane;
    // adj staging: thread t covers row (t>>4), physical granule (t&15);
    // source pre-swizzled (involution; reader XORs the same way).
    int ar = t >> 4, ag = t & 15;
    const float* asrc = adj + (size_t)(row0 + ar) * NN + (((ag ^ (ar & 7))) << 2);

#define STAGE(BUF, JC)                                                   \
    do {                                                                 \
        gload_lds16(hsrc + (JC), (_Float16*)(BUF) + (w << 9));           \
        gload_lds4(dsrc + (JC), (float*)((BUF) + 8192) + (w << 6));      \
        gload_lds16(asrc + (JC), (float*)((BUF) + 10240) + (w << 8));    \
    } while (0)

    STAGE(bufP, 0);                            // prologue: chunk 0 in flight

    // md = max over partial-max slots for (b, head w); butterfly reduce
    constexpr int NT = (MODE == 0) ? 32 : 16;
    float md = pmaxd[((size_t)b * NT + (lane & (NT - 1))) * 8 + w];
#pragma unroll
    for (int off = NT >> 1; off; off >>= 1) md = fmaxf(md, __shfl_xor(md, off));

    float svA = s[((size_t)b * NN + myrow) * 8 + w];
    float svB = s[((size_t)b * NN + myrow + 16) * 8 + w];
    float MA = fmaxf(svA + md, 0.f);
    float MB = fmaxf(svB + md, 0.f);
    // per-row softmax factors (all <= 1): c0 = exp(sv+md-M), cb = exp(.2(sv+md)-M)
    float c0A = __expf(svA + md - MA), cbA = __expf(0.2f * (svA + md) - MA);
    float c0B = __expf(svB + md - MB), cbB = __expf(0.2f * (svB + md) - MB);
    int rq8 = rq * 8;

    f16x8 ones;
#pragma unroll
    for (int e = 0; e < 8; ++e) ones[e] = (_Float16)1.0f;

    f32x4 accA[4], accB[4], accrsA, accrsB;
#pragma unroll
    for (int e = 0; e < 4; ++e) { accrsA[e] = 0.f; accrsB[e] = 0.f; }
#pragma unroll
    for (int ft = 0; ft < 4; ++ft)
#pragma unroll
        for (int e = 0; e < 4; ++e) { accA[ft][e] = 0.f; accB[ft][e] = 0.f; }

    __syncthreads();                           // buf0 staged

    for (int jcx = 0; jcx < 8; ++jcx) {
        int jc = jcx * 64;
        char* cur = (jcx & 1) ? bufQ : bufP;
        char* nxt = (jcx & 1) ? bufP : bufQ;
        if (jcx < 7) STAGE(nxt, jc + 64);      // lands during this chunk
        const _Float16* hTc = (const _Float16*)cur;
        const float* ddl = (const float*)(cur + 8192) + (w << 6);
        const float* adl = (const float*)(cur + 10240);
        const float* arA = adl + cn * 64;
        const float* arB = adl + (16 + cn) * 64;
        int xA = cn & 7;
        // ---- per-wave E/Eb tables for this chunk (2 exps/lane)
        float* Et = (float*)(smem + 36864) + (w << 7);
        {
            float ddj = ddl[lane];
            Et[lane]      = __expf(ddj - md);
            Et[lane + 64] = __expf(0.2f * (ddj - md));
        }
        asm volatile("s_waitcnt lgkmcnt(0)" ::: "memory");  // same-wave RAW
#pragma unroll
        for (int ks = 0; ks < 2; ++ks) {
            int jo = ks * 32 + rq8;
            float dd[8], avA[8], avB[8], Ev[8], Ebv[8];
            *(float4*)&dd[0] = *(const float4*)(ddl + jo);
            *(float4*)&dd[4] = *(const float4*)(ddl + jo + 4);
            *(float4*)&Ev[0]  = *(const float4*)(Et + jo);
            *(float4*)&Ev[4]  = *(const float4*)(Et + jo + 4);
            *(float4*)&Ebv[0] = *(const float4*)(Et + 64 + jo);
            *(float4*)&Ebv[4] = *(const float4*)(Et + 64 + jo + 4);
            int G0 = jo >> 2;                  // granule index of jo
            *(float4*)&avA[0] = *(const float4*)(arA + ((G0 ^ xA) << 2));
            *(float4*)&avA[4] = *(const float4*)(arA + (((G0 + 1) ^ xA) << 2));
            *(float4*)&avB[0] = *(const float4*)(arB + ((G0 ^ xA) << 2));
            *(float4*)&avB[4] = *(const float4*)(arB + (((G0 + 1) ^ xA) << 2));
            int relA = myrow - (jc + jo);
            int relB = relA + 16;
            AF aA, aB;
            PBUILD(aA, svA, c0A, cbA, avA, relA, dd, Ev, Ebv);
            PBUILD(aB, svB, c0B, cbB, avB, relB, dd, Ev, Ebv);
            accrsA = MFMA16(aA.v, ones, accrsA);
            accrsB = MFMA16(aB.v, ones, accrsB);
#pragma unroll
            for (int ft = 0; ft < 4; ++ft) {   // 1 bh read -> 2 MFMAs
                int f = ft * 16 + cn;
                f16x8 bh = *(const f16x8*)&hTc[f * 64 + (((ks * 4 + rq) ^ (f & 7)) * 8)];
                accA[ft] = MFMA16(aA.v, bh, accA[ft]);
                accB[ft] = MFMA16(aB.v, bh, accB[ft]);
            }
        }
        __syncthreads();                       // drains next-chunk staging too
    }
#undef STAGE

    float invrA[4], invrB[4];
#pragma unroll
    for (int r = 0; r < 4; ++r) {
        invrA[r] = 1.0f / accrsA[r];
        invrB[r] = 1.0f / accrsB[r];
    }

    if (MODE == 0) {
        _Float16* x1all = (_Float16*)smem;     // [8][32][64] fp16 = 32KB
#pragma unroll
        for (int rt = 0; rt < 2; ++rt)
#pragma unroll
            for (int ft = 0; ft < 4; ++ft)
#pragma unroll
                for (int r = 0; r < 4; ++r) {
                    int il = rt * 16 + rq * 4 + r;
                    float v = rt ? accB[ft][r] * invrB[r]
                                 : accA[ft][r] * invrA[r];
                    v = v > 0.f ? v : __expf(v) - 1.f;   // ELU
                    int f = ft * 16 + cn;
                    x1all[w * 2048 + il * 64 + (((f >> 3) ^ (il & 7)) * 8) + (f & 7)] =
                        (_Float16)v;
                }
        __syncthreads();
        f32x4 g1A, g1B;
#pragma unroll
        for (int e = 0; e < 4; ++e) { g1A[e] = 0.f; g1B[e] = 0.f; }
        int nn = (w & 3) * 16 + cn, kh = w >> 2;
        const _Float16* wb = W1T + (size_t)nn * 512;
#pragma unroll
        for (int kc2 = 0; kc2 < 4; ++kc2) {
            int kc = kh * 4 + kc2;
#pragma unroll
            for (int ks = 0; ks < 2; ++ks) {
                f16x8 bh = *(const f16x8*)(wb + kc * 64 +
                                           (((ks * 4 + rq) ^ (nn & 7)) * 8));
                f16x8 ahA = *(const f16x8*)&x1all[kc * 2048 + cn * 64 +
                                                  (((ks * 4 + rq) ^ (cn & 7)) * 8)];
                f16x8 ahB = *(const f16x8*)&x1all[kc * 2048 + (16 + cn) * 64 +
                                                  (((ks * 4 + rq) ^ (cn & 7)) * 8)];
                g1A = MFMA16(ahA, bh, g1A);
                g1B = MFMA16(ahB, bh, g1B);
            }
        }
        __syncthreads();                       // x1all reads done
        float* ct = (float*)smem;              // [2][32][66] = 16.9KB
        float* asd_f = (float*)(smem + 33280); // 4KB
        float* dmax = (float*)(smem + 37376);  // 1KB (Et dead)
#pragma unroll
        for (int r = 0; r < 4; ++r) {
            ct[kh * 2112 + (rq * 4 + r) * 66 + nn] = g1A[r];
            ct[kh * 2112 + (16 + rq * 4 + r) * 66 + nn] = g1B[r];
        }
        if (t < 256)
            ((float4*)asd_f)[t] = (t < 128) ? ((const float4*)a_src)[t]
                                            : ((const float4*)a_dst)[t - 128];
        __syncthreads();
        for (int idx = t; idx < 2112; idx += 512) ct[idx] += ct[2112 + idx];
        __syncthreads();
        epi32(ct, asd_f, row0, t, s_out, dTg_out, hpT_out, dmax, pmax_out);
    } else {
        float* red = (float*)smem;             // [4][32][64] fp32 = 32KB
#pragma unroll
        for (int ph = 0; ph < 2; ++ph) {
            if ((w >> 2) == ph) {
#pragma unroll
                for (int rt = 0; rt < 2; ++rt)
#pragma unroll
                    for (int ft = 0; ft < 4; ++ft)
#pragma unroll
                        for (int r = 0; r < 4; ++r) {
                            int il = rt * 16 + rq * 4 + r;
                            float v = rt ? accB[ft][r] * invrB[r]
                                         : accA[ft][r] * invrA[r];
                            int off = (w & 3) * 2048 + il * 64 + ft * 16 + cn;
                            if (ph == 0) red[off] = v;
                            else         red[off] += v;
                        }
            }
            __syncthreads();
        }
#pragma unroll
        for (int u = 0; u < 4; ++u) {
            int idx = t + u * 512;
            int il = idx >> 6, f = idx & 63;
            float sum = red[il * 64 + f] + red[2048 + il * 64 + f]
                      + red[4096 + il * 64 + f] + red[6144 + il * 64 + f];
            o_f[((size_t)b * NN + i0 + il) * 64 + f] = sum * 0.125f;
        }
    }
}

extern "C" void kernel_launch(void* const* d_in, const int* in_sizes, int n_in,
                              void* d_out, int out_size, void* d_ws, size_t ws_size,
                              hipStream_t stream) {
    const float* x      = (const float*)d_in[0];
    const float* adj    = (const float*)d_in[1];
    const float* W0     = (const float*)d_in[4];
    const float* a_src0 = (const float*)d_in[5];
    const float* a_dst0 = (const float*)d_in[6];
    const float* W1     = (const float*)d_in[7];
    const float* a_src1 = (const float*)d_in[8];
    const float* a_dst1 = (const float*)d_in[9];
    float* out = (float*)d_out;

    float* ws = (float*)d_ws;
    const size_t R = (size_t)BB * NN;            // 16384 rows
    const size_t BHN = (size_t)BB * 8 * NN;      // 131072
    float* s0    = ws;                           // R*8
    float* dTg0  = s0 + R * 8;
    float* s1    = dTg0 + BHN;
    float* dTg1  = s1 + R * 8;
    float* pmax0 = dTg1 + BHN;                   // 32*32*8 = 8192
    float* pmax1 = pmax0 + 8192;                 // 32*16*8 = 4096
    _Float16* hp0T = (_Float16*)(pmax1 + 4096);  // 32*64*512
    _Float16* hp1T = hp0T + (size_t)BB * 64 * NN;
    _Float16* W1T  = hp1T + (size_t)BB * 64 * NN;   // 64*512

    k_front<<<1024, 256, 0, stream>>>(x, W0, W1, W1T, a_src0, a_dst0,
                                      s0, dTg0, hp0T, pmax0);
    k_attn_fused<0><<<512, 512, 0, stream>>>(s0, dTg0, pmax0, hp0T, adj,
                                             W1T, a_src1, a_dst1,
                                             s1, dTg1, hp1T, pmax1, nullptr);
    k_attn_fused<1><<<512, 512, 0, stream>>>(s1, dTg1, pmax1, hp1T, adj,
                                             nullptr, nullptr, nullptr,
                                             nullptr, nullptr, nullptr, nullptr, out);
}